// Round 6
// baseline (1879.433 us; speedup 1.0000x reference)
//
#include <hip/hip_runtime.h>
#include <math.h>

#define BB 32768
#define EE 16
#define HH 128
#define KC 144        // EE + HH
#define NG 512        // 4*HH
#define OBS 8
#define NSTEP 19
#define TPB 256
#define ROWS 64       // rows per block
#define RPW 16        // rows per wave (4 waves/block)
#define NQ 36         // KC/4 k-quads

__device__ __forceinline__ float sigm(float x) {
    return __builtin_amdgcn_rcpf(1.0f + __expf(-x));
}
__device__ __forceinline__ float fast_tanh(float x) {
    float e = __expf(-2.0f * x);
    return (1.0f - e) * __builtin_amdgcn_rcpf(1.0f + e);
}

// Pack Wt[k][j*4+g] = (k<EE ? W_ih : W_hh)[col=g*128+j][k(-EE)]; bt[j*4+g] = b_ih+b_hh.
__global__ __launch_bounds__(256) void k_prep(
    const float* __restrict__ W_ih, const float* __restrict__ b_ih,
    const float* __restrict__ W_hh, const float* __restrict__ b_hh,
    float* __restrict__ Wt, float* __restrict__ bt)
{
    int idx = blockIdx.x * 256 + threadIdx.x;
    if (idx < KC * NG) {
        int k = idx >> 9, jg = idx & 511;
        int j = jg >> 2, g = jg & 3, col = g * HH + j;
        Wt[idx] = (k < EE) ? W_ih[col * EE + k] : W_hh[col * HH + (k - EE)];
    }
    if (idx < NG) {
        int j = idx >> 2, g = idx & 3, col = g * HH + j;
        bt[idx] = b_ih[col] + b_hh[col];
    }
}

// waves_per_eu(2,2): pin occupancy to 2 waves/SIMD so the allocator budgets
// 256 VGPRs/wave -- RPW=16 needs ~212 live regs (acc 128 + w 32 + c 32).
// launch_bounds(256,2) alone let the allocator target 128 VGPRs and spill
// the accumulators to scratch (round 5: FETCH 878 GB of spill traffic).
__global__ __attribute__((amdgpu_waves_per_eu(2, 2))) __launch_bounds__(TPB) void k_lstm(
    const float* __restrict__ obs,
    const float* __restrict__ W_emb, const float* __restrict__ b_emb,
    const float* __restrict__ Wt,    const float* __restrict__ bt,
    const float* __restrict__ W_out, const float* __restrict__ b_out,
    float* __restrict__ out)
{
    __shared__ float xh[ROWS * KC];      // per-wave-private row slices
    __shared__ float plpp[ROWS * 4];     // pl0 pl1 pp0 pp1 per row

    const int t  = threadIdx.x;
    const int tc = t & 63;               // lane
    const int tr = t >> 6;               // wave id 0..3
    const int rowL0 = tr * RPW;          // first local row of this wave
    const int row0  = blockIdx.x * ROWS + rowL0;

    // per-thread column bias (cols jg = tc*8 .. tc*8+7)
    float bias8[8];
    {
        float4 b0 = *reinterpret_cast<const float4*>(&bt[tc * 8]);
        float4 b1 = *reinterpret_cast<const float4*>(&bt[tc * 8 + 4]);
        bias8[0]=b0.x; bias8[1]=b0.y; bias8[2]=b0.z; bias8[3]=b0.w;
        bias8[4]=b1.x; bias8[5]=b1.y; bias8[6]=b1.z; bias8[7]=b1.w;
    }
    // readout weights for this lane's j-pair
    const float wo00 = W_out[0 * HH + tc * 2], wo01 = W_out[0 * HH + tc * 2 + 1];
    const float wo10 = W_out[1 * HH + tc * 2], wo11 = W_out[1 * HH + tc * 2 + 1];
    const float bo0 = b_out[0], bo1 = b_out[1];
    // embed weights for this lane's e-slot (e = tc&15)
    const int e_ = tc & 15;
    const float we0 = W_emb[2 * e_], we1 = W_emb[2 * e_ + 1], be = b_emb[e_];

    float c[RPW][2];
#pragma unroll
    for (int r = 0; r < RPW; r++) { c[r][0] = 0.0f; c[r][1] = 0.0f; }

    // zero own h region (wave-private; no barrier needed anywhere)
#pragma unroll
    for (int r = 0; r < RPW; r++) {
        xh[(rowL0 + r) * KC + EE + tc * 2]     = 0.0f;
        xh[(rowL0 + r) * KC + EE + tc * 2 + 1] = 0.0f;
    }

#pragma unroll 1
    for (int s = 0; s < NSTEP; s++) {
        // ---------- embed: relu(W_emb@delta + b_emb), rows wave-private ----------
#pragma unroll
        for (int pass = 0; pass < 4; pass++) {
            int rl = (tc >> 4) + pass * 4;          // local row 0..15
            int grow = row0 + rl;
            float d0, d1;
            if (s < OBS) {
                d0 = obs[(size_t)(s + 1) * BB * 2 + grow * 2]     - obs[(size_t)s * BB * 2 + grow * 2];
                d1 = obs[(size_t)(s + 1) * BB * 2 + grow * 2 + 1] - obs[(size_t)s * BB * 2 + grow * 2 + 1];
            } else {
                const float* p4 = &plpp[(rowL0 + rl) * 4];
                d0 = p4[0] - p4[2];
                d1 = p4[1] - p4[3];
            }
            float v = be + d0 * we0 + d1 * we1;
            xh[(rowL0 + rl) * KC + e_] = v > 0.0f ? v : 0.0f;
        }

        // ---------- gates: acc[r][cc], cc = jj*4+g ----------
        float acc[RPW][8];
#pragma unroll
        for (int r = 0; r < RPW; r++)
#pragma unroll
            for (int cc = 0; cc < 8; cc++) acc[r][cc] = bias8[cc];

#pragma unroll 1
        for (int kq = 0; kq < NQ; kq++) {
            // 4 consecutive k-rows of Wt for this lane's 8 cols (independent of r)
            const float* wrow = &Wt[(size_t)(kq * 4) * NG + tc * 8];
            float4 w0a = *reinterpret_cast<const float4*>(wrow);
            float4 w0b = *reinterpret_cast<const float4*>(wrow + 4);
            float4 w1a = *reinterpret_cast<const float4*>(wrow + NG);
            float4 w1b = *reinterpret_cast<const float4*>(wrow + NG + 4);
            float4 w2a = *reinterpret_cast<const float4*>(wrow + 2 * NG);
            float4 w2b = *reinterpret_cast<const float4*>(wrow + 2 * NG + 4);
            float4 w3a = *reinterpret_cast<const float4*>(wrow + 3 * NG);
            float4 w3b = *reinterpret_cast<const float4*>(wrow + 3 * NG + 4);
#pragma unroll
            for (int r = 0; r < RPW; r++) {
                float4 xv = *reinterpret_cast<const float4*>(&xh[(rowL0 + r) * KC + kq * 4]);
                acc[r][0] += xv.x * w0a.x; acc[r][1] += xv.x * w0a.y;
                acc[r][2] += xv.x * w0a.z; acc[r][3] += xv.x * w0a.w;
                acc[r][4] += xv.x * w0b.x; acc[r][5] += xv.x * w0b.y;
                acc[r][6] += xv.x * w0b.z; acc[r][7] += xv.x * w0b.w;

                acc[r][0] += xv.y * w1a.x; acc[r][1] += xv.y * w1a.y;
                acc[r][2] += xv.y * w1a.z; acc[r][3] += xv.y * w1a.w;
                acc[r][4] += xv.y * w1b.x; acc[r][5] += xv.y * w1b.y;
                acc[r][6] += xv.y * w1b.z; acc[r][7] += xv.y * w1b.w;

                acc[r][0] += xv.z * w2a.x; acc[r][1] += xv.z * w2a.y;
                acc[r][2] += xv.z * w2a.z; acc[r][3] += xv.z * w2a.w;
                acc[r][4] += xv.z * w2b.x; acc[r][5] += xv.z * w2b.y;
                acc[r][6] += xv.z * w2b.z; acc[r][7] += xv.z * w2b.w;

                acc[r][0] += xv.w * w3a.x; acc[r][1] += xv.w * w3a.y;
                acc[r][2] += xv.w * w3a.z; acc[r][3] += xv.w * w3a.w;
                acc[r][4] += xv.w * w3b.x; acc[r][5] += xv.w * w3b.y;
                acc[r][6] += xv.w * w3b.z; acc[r][7] += xv.w * w3b.w;
            }
        }

        // ---------- cell update + h writeback + readout partials ----------
        float red[RPW][2];
#pragma unroll
        for (int r = 0; r < RPW; r++) {
            float h0, h1;
            {
                float gi = sigm(acc[r][0]), gf = sigm(acc[r][1]);
                float gg = fast_tanh(acc[r][2]), go = sigm(acc[r][3]);
                float cn = gf * c[r][0] + gi * gg;
                c[r][0] = cn;
                h0 = go * fast_tanh(cn);
            }
            {
                float gi = sigm(acc[r][4]), gf = sigm(acc[r][5]);
                float gg = fast_tanh(acc[r][6]), go = sigm(acc[r][7]);
                float cn = gf * c[r][1] + gi * gg;
                c[r][1] = cn;
                h1 = go * fast_tanh(cn);
            }
            *reinterpret_cast<float2*>(&xh[(rowL0 + r) * KC + EE + tc * 2]) = make_float2(h0, h1);
            red[r][0] = h0 * wo00 + h1 * wo01;
            red[r][1] = h0 * wo10 + h1 * wo11;
        }

        // butterfly reduce over the 64 lanes (rows are wave-private)
#pragma unroll
        for (int mask = 1; mask < 64; mask <<= 1) {
#pragma unroll
            for (int r = 0; r < RPW; r++) {
                red[r][0] += __shfl_xor(red[r][0], mask, 64);
                red[r][1] += __shfl_xor(red[r][1], mask, 64);
            }
        }

        if (tc == 0) {
#pragma unroll
            for (int r = 0; r < RPW; r++) {
                int grow = row0 + r;
#pragma unroll
                for (int oc = 0; oc < 2; oc++) {
                    float base = (s < OBS)
                        ? obs[(size_t)(s + 1) * BB * 2 + grow * 2 + oc]
                        : plpp[(rowL0 + r) * 4 + oc];
                    float pos = base + red[r][oc] + (oc ? bo1 : bo0);
                    out[((size_t)s * BB + grow) * 2 + oc] = pos;
                    plpp[(rowL0 + r) * 4 + 2 + oc] = plpp[(rowL0 + r) * 4 + oc];  // pp <- pl
                    plpp[(rowL0 + r) * 4 + oc]     = pos;                          // pl <- pos
                }
            }
        }
        // no __syncthreads: all state (xh rows, plpp rows, c) is wave-private
    }
}

extern "C" void kernel_launch(void* const* d_in, const int* in_sizes, int n_in,
                              void* d_out, int out_size, void* d_ws, size_t ws_size,
                              hipStream_t stream)
{
    const float* obs   = (const float*)d_in[0];
    const float* W_emb = (const float*)d_in[1];
    const float* b_emb = (const float*)d_in[2];
    const float* W_ih  = (const float*)d_in[3];
    const float* b_ih  = (const float*)d_in[4];
    const float* W_hh  = (const float*)d_in[5];
    const float* b_hh  = (const float*)d_in[6];
    const float* W_out = (const float*)d_in[7];
    const float* b_out = (const float*)d_in[8];
    float* out = (float*)d_out;

    float* Wt = (float*)d_ws;                 // [144][512]
    float* bt = Wt + KC * NG;                 // [512]

    hipLaunchKernelGGL(k_prep, dim3((KC * NG + 255) / 256), dim3(256), 0, stream,
                       W_ih, b_ih, W_hh, b_hh, Wt, bt);

    hipLaunchKernelGGL(k_lstm, dim3(BB / ROWS), dim3(TPB), 0, stream,
                       obs, W_emb, b_emb, Wt, bt, W_out, b_out, out);
}

// Round 7
// 366.857 us; speedup vs baseline: 5.1231x; 5.1231x over previous
//
#include <hip/hip_runtime.h>
#include <hip/hip_bf16.h>
#include <math.h>

#define BB 32768
#define EE 16
#define HH 128
#define KP 160          // padded K: 16 x + 128 h + 16 zeros
#define XS 168          // xh row stride (bf16 elems): 168*2B=336B -> bank-spread, 16B-aligned
#define OBS 8
#define NSTEP 19
#define TPB 1024
#define MROWS 64        // batch rows per block
#define KT 5            // K-tiles of 32

typedef short s16x8 __attribute__((ext_vector_type(8)));   // 8 bf16 (4 VGPRs), MFMA A/B frag
typedef float f32x4 __attribute__((ext_vector_type(4)));   // MFMA C/D frag

__device__ __forceinline__ float sigm(float x){ return __builtin_amdgcn_rcpf(1.0f + __expf(-x)); }
__device__ __forceinline__ float ftanh(float x){ float e = __expf(-2.f*x); return (1.f-e)*__builtin_amdgcn_rcpf(1.f+e); }
__device__ __forceinline__ unsigned short f2b(float x){
    __hip_bfloat16 h = __float2bfloat16(x);
    return *reinterpret_cast<unsigned short*>(&h);
}
__device__ __forceinline__ float b2f_(unsigned short u){ return __uint_as_float(((unsigned int)u) << 16); }

// Pack W_cat = [W_ih | W_hh] (K=144, zero-pad to 160) into MFMA A-operand fragment order,
// split into bf16 hi + lo.  Frag (JT 0..31, kt 0..4): lane l, elem j holds
//   W_cat[k = kt*32 + (l>>4)*8 + j][jg = JT*16 + (l&15)],  jg = 4*j_hidden + gate.
__global__ __launch_bounds__(256) void k_prep(
    const float* __restrict__ W_ih, const float* __restrict__ W_hh,
    unsigned short* __restrict__ Whi, unsigned short* __restrict__ Wlo)
{
    int idx = blockIdx.x * 256 + threadIdx.x;      // exactly 32*5*64*8 = 81920 threads
    int j    = idx & 7;
    int lane = (idx >> 3) & 63;
    int kt   = (idx >> 9) % KT;
    int JT   = idx / (KT * 512);
    int k  = kt * 32 + ((lane >> 4) << 3) + j;
    int jg = JT * 16 + (lane & 15);
    int col = (jg & 3) * HH + (jg >> 2);           // original gate row: g*128 + j_hidden
    float wv = 0.f;
    if (k < EE)            wv = W_ih[col * EE + k];
    else if (k < EE + HH)  wv = W_hh[col * HH + (k - EE)];
    unsigned short hi = f2b(wv);
    Whi[idx] = hi;
    Wlo[idx] = f2b(wv - b2f_(hi));
}

// Occupancy: attribute-only (NO __launch_bounds__ -- it overrides waves_per_eu, see R5/R6
// spills).  waves_per_eu(4,4) pins 4 waves/SIMD -> 128-VGPR budget for ~115 live regs.
__global__ __attribute__((amdgpu_flat_work_group_size(TPB, TPB)))
           __attribute__((amdgpu_waves_per_eu(4, 4)))
void k_lstm(
    const float* __restrict__ obs,
    const float* __restrict__ W_emb, const float* __restrict__ b_emb,
    const float* __restrict__ b_ih,  const float* __restrict__ b_hh,
    const unsigned short* __restrict__ Whi, const unsigned short* __restrict__ Wlo,
    const float* __restrict__ W_out, const float* __restrict__ b_out,
    float* __restrict__ out)
{
    __shared__ unsigned short xhh[MROWS * XS];   // bf16 hi of [x(16)|h(128)|0(16)|pad]
    __shared__ unsigned short xhl[MROWS * XS];   // bf16 lo
    __shared__ float wout[2 * HH];
    __shared__ float wemb[EE * 2];
    __shared__ float bemb[EE];

    const int t    = threadIdx.x;
    const int lane = t & 63;
    const int w    = t >> 6;                     // wave 0..15: gate-cols jg in [w*32,(w+1)*32)
    const int row0 = blockIdx.x * MROWS;

    if (t < 2 * HH) wout[t] = W_out[t];          // rows 0,1 of W_out (contiguous)
    if (t < EE * 2) wemb[t] = W_emb[t];
    if (t < EE)     bemb[t] = b_emb[t];
    for (int i = t; i < MROWS * XS; i += TPB) { xhh[i] = 0; xhl[i] = 0; }

    // per-lane gate biases: acc[mt] reg r <-> jg = (2w+mt)*16 + (lane>>4)*4 + r
    f32x4 bias[2];
#pragma unroll
    for (int mt = 0; mt < 2; mt++)
#pragma unroll
        for (int r = 0; r < 4; r++) {
            int jg  = (2 * w + mt) * 16 + ((lane >> 4) << 2) + r;
            int col = (jg & 3) * HH + (jg >> 2);
            bias[mt][r] = b_ih[col] + b_hh[col];
        }
    const float bo0 = b_out[0], bo1 = b_out[1];

    // readout/embed mapping: row = t>>4 (64 rows), rp = t&15 (16-way partials / 16 embed dims)
    const int rrow = t >> 4;
    const int rp   = t & 15;
    const int grow = row0 + rrow;

    const unsigned short* aHi = Whi + ((size_t)(2 * w) * KT) * 512 + (lane << 3);
    const unsigned short* aLo = Wlo + ((size_t)(2 * w) * KT) * 512 + (lane << 3);

    float c8[2][4];
#pragma unroll
    for (int mt = 0; mt < 2; mt++)
#pragma unroll
        for (int nt = 0; nt < 4; nt++) c8[mt][nt] = 0.f;
    float pl0 = 0.f, pl1 = 0.f;                  // p_last (per-row, maintained by all 16 rp-threads)

    __syncthreads();

    // initial embed x[0] from obs delta: thread (rrow, rp=e)
    {
        float d0 = obs[(size_t)1 * BB * 2 + grow * 2 + 0] - obs[(size_t)0 * BB * 2 + grow * 2 + 0];
        float d1 = obs[(size_t)1 * BB * 2 + grow * 2 + 1] - obs[(size_t)0 * BB * 2 + grow * 2 + 1];
        float v = bemb[rp] + d0 * wemb[2 * rp] + d1 * wemb[2 * rp + 1];
        v = v > 0.f ? v : 0.f;
        unsigned short hi = f2b(v);
        xhh[rrow * XS + rp] = hi;
        xhl[rrow * XS + rp] = f2b(v - b2f_(hi));
    }
    __syncthreads();

#pragma unroll 1
    for (int s = 0; s < NSTEP; s++) {
        // ---- gates GEMM: D[jg][row] = sum_k Wcat[k][jg] * xh[row][k]  (3-term bf16 split) ----
        f32x4 acc[2][4];
#pragma unroll
        for (int mt = 0; mt < 2; mt++)
#pragma unroll
            for (int nt = 0; nt < 4; nt++) acc[mt][nt] = bias[mt];

#pragma unroll 1
        for (int kt = 0; kt < KT; kt++) {
            const int fo0 = (0 * KT + kt) << 9;
            const int fo1 = (1 * KT + kt) << 9;
            s16x8 ah0 = *(const s16x8*)(aHi + fo0);
            s16x8 ah1 = *(const s16x8*)(aHi + fo1);
            s16x8 al0 = *(const s16x8*)(aLo + fo0);
            s16x8 al1 = *(const s16x8*)(aLo + fo1);
            const int koff = (kt << 5) + ((lane >> 4) << 3);
            const unsigned short* bhp = &xhh[(lane & 15) * XS + koff];
            const unsigned short* blp = &xhl[(lane & 15) * XS + koff];
#pragma unroll
            for (int nt = 0; nt < 4; nt++) {
                s16x8 bH = *(const s16x8*)(bhp + nt * 16 * XS);
                acc[0][nt] = __builtin_amdgcn_mfma_f32_16x16x32_bf16(ah0, bH, acc[0][nt], 0, 0, 0);
                acc[1][nt] = __builtin_amdgcn_mfma_f32_16x16x32_bf16(ah1, bH, acc[1][nt], 0, 0, 0);
                acc[0][nt] = __builtin_amdgcn_mfma_f32_16x16x32_bf16(al0, bH, acc[0][nt], 0, 0, 0);
                acc[1][nt] = __builtin_amdgcn_mfma_f32_16x16x32_bf16(al1, bH, acc[1][nt], 0, 0, 0);
            }
#pragma unroll
            for (int nt = 0; nt < 4; nt++) {
                s16x8 bL = *(const s16x8*)(blp + nt * 16 * XS);
                acc[0][nt] = __builtin_amdgcn_mfma_f32_16x16x32_bf16(ah0, bL, acc[0][nt], 0, 0, 0);
                acc[1][nt] = __builtin_amdgcn_mfma_f32_16x16x32_bf16(ah1, bL, acc[1][nt], 0, 0, 0);
            }
        }

        // ---- cell update: lane's 4 acc regs = (i,f,g,o) of hidden j -- no shuffles ----
        float hnew[2][4];
#pragma unroll
        for (int mt = 0; mt < 2; mt++)
#pragma unroll
            for (int nt = 0; nt < 4; nt++) {
                f32x4 g = acc[mt][nt];
                float cn = sigm(g[1]) * c8[mt][nt] + sigm(g[0]) * ftanh(g[2]);
                c8[mt][nt] = cn;
                hnew[mt][nt] = sigm(g[3]) * ftanh(cn);
            }

        __syncthreads();   // B_A: all waves finished reading xh for this step

#pragma unroll
        for (int mt = 0; mt < 2; mt++)
#pragma unroll
            for (int nt = 0; nt < 4; nt++) {
                int row = nt * 16 + (lane & 15);
                int j   = 8 * w + mt * 4 + (lane >> 4);
                float h = hnew[mt][nt];
                unsigned short hi = f2b(h);
                xhh[row * XS + EE + j] = hi;
                xhl[row * XS + EE + j] = f2b(h - b2f_(hi));
            }

        __syncthreads();   // B_B: new h visible to all

        // ---- readout + position + next-step embed ----
        {
            const unsigned short* ph = &xhh[rrow * XS + EE + (rp << 3)];
            const unsigned short* pq = &xhl[rrow * XS + EE + (rp << 3)];
            s16x8 uh = *(const s16x8*)ph;
            s16x8 ul = *(const s16x8*)pq;
            float4 w0a = *(const float4*)&wout[(rp << 3)];
            float4 w0b = *(const float4*)&wout[(rp << 3) + 4];
            float4 w1a = *(const float4*)&wout[HH + (rp << 3)];
            float4 w1b = *(const float4*)&wout[HH + (rp << 3) + 4];
            float hv[8];
#pragma unroll
            for (int q = 0; q < 8; q++)
                hv[q] = b2f_((unsigned short)uh[q]) + b2f_((unsigned short)ul[q]);
            float r0 = hv[0]*w0a.x + hv[1]*w0a.y + hv[2]*w0a.z + hv[3]*w0a.w
                     + hv[4]*w0b.x + hv[5]*w0b.y + hv[6]*w0b.z + hv[7]*w0b.w;
            float r1 = hv[0]*w1a.x + hv[1]*w1a.y + hv[2]*w1a.z + hv[3]*w1a.w
                     + hv[4]*w1b.x + hv[5]*w1b.y + hv[6]*w1b.z + hv[7]*w1b.w;
#pragma unroll
            for (int m = 1; m < 16; m <<= 1) {
                r0 += __shfl_xor(r0, m, 64);
                r1 += __shfl_xor(r1, m, 64);
            }
            float base0, base1;
            if (s < OBS) {
                base0 = obs[(size_t)(s + 1) * BB * 2 + grow * 2 + 0];
                base1 = obs[(size_t)(s + 1) * BB * 2 + grow * 2 + 1];
            } else {
                base0 = pl0; base1 = pl1;
            }
            float pos0 = base0 + r0 + bo0;
            float pos1 = base1 + r1 + bo1;
            if (rp == 0) {
                out[((size_t)s * BB + grow) * 2 + 0] = pos0;
                out[((size_t)s * BB + grow) * 2 + 1] = pos1;
            }
            if (s + 1 < NSTEP) {
                float d0, d1;
                if (s + 1 < OBS) {
                    d0 = obs[(size_t)(s + 2) * BB * 2 + grow * 2 + 0] - obs[(size_t)(s + 1) * BB * 2 + grow * 2 + 0];
                    d1 = obs[(size_t)(s + 2) * BB * 2 + grow * 2 + 1] - obs[(size_t)(s + 1) * BB * 2 + grow * 2 + 1];
                } else {
                    d0 = pos0 - pl0;            // p_last_new - p_prev_new
                    d1 = pos1 - pl1;
                }
                float v = bemb[rp] + d0 * wemb[2 * rp] + d1 * wemb[2 * rp + 1];
                v = v > 0.f ? v : 0.f;
                unsigned short hi = f2b(v);
                xhh[rrow * XS + rp] = hi;       // x-region write; disjoint from h-reads above
                xhl[rrow * XS + rp] = f2b(v - b2f_(hi));
            }
            pl0 = pos0; pl1 = pos1;
        }
        __syncthreads();   // B_C: x[s+1] + plpp consistent before next GEMM
    }
}

extern "C" void kernel_launch(void* const* d_in, const int* in_sizes, int n_in,
                              void* d_out, int out_size, void* d_ws, size_t ws_size,
                              hipStream_t stream)
{
    const float* obs   = (const float*)d_in[0];
    const float* W_emb = (const float*)d_in[1];
    const float* b_emb = (const float*)d_in[2];
    const float* W_ih  = (const float*)d_in[3];
    const float* b_ih  = (const float*)d_in[4];
    const float* W_hh  = (const float*)d_in[5];
    const float* b_hh  = (const float*)d_in[6];
    const float* W_out = (const float*)d_in[7];
    const float* b_out = (const float*)d_in[8];
    float* out = (float*)d_out;

    unsigned short* Whi = (unsigned short*)d_ws;        // 32*5*64*8 = 81920 bf16
    unsigned short* Wlo = Whi + 32 * KT * 64 * 8;       // another 81920

    hipLaunchKernelGGL(k_prep, dim3(32 * KT * 64 * 8 / 256), dim3(256), 0, stream,
                       W_ih, W_hh, Whi, Wlo);

    hipLaunchKernelGGL(k_lstm, dim3(BB / MROWS), dim3(TPB), 0, stream,
                       obs, W_emb, b_emb, b_ih, b_hh, Whi, Wlo, W_out, b_out, out);
}